// Round 6
// baseline (43.484 us; speedup 1.0000x reference)
//
#include <hip/hip_runtime.h>
#include <hip/hip_bf16.h>

#define NN 7
#define HH 16
#define RR 64
#define CC 8
#define NBINS (NN * RR * NN)   // 3136

#define HIST_BLOCK 1024
#define HIST_GRID  256                      // exactly 1 block per CU
#define NT (HIST_GRID * HIST_BLOCK)         // 262144 threads
#define DEPTH 8                             // ceil(E4/NT)=8 for E=8M

// ---------------------------------------------------------------------------
// Kernel 1: histogram edges into (dst, rel, src) bins in LDS.
// Full-coverage depth-8 barrage: all 24 dwordx4 loads issued back-to-back
// (clamped indices), then 32 predicated LDS atomics (addend 0 if OOB).
// No serial remainder loop. Block-private histogram -> plain stores.
// ---------------------------------------------------------------------------
__global__ __launch_bounds__(HIST_BLOCK) void rgcn_hist(
    const int* __restrict__ src, const int* __restrict__ dst,
    const int* __restrict__ et, int E, int* __restrict__ part) {
    __shared__ int bins[NBINS];
    for (int i = threadIdx.x; i < NBINS; i += HIST_BLOCK) bins[i] = 0;
    __syncthreads();

    const int tid = blockIdx.x * HIST_BLOCK + threadIdx.x;
    const int E4 = E >> 2;
    const int4* s4 = reinterpret_cast<const int4*>(src);
    const int4* d4 = reinterpret_cast<const int4*>(dst);
    const int4* t4 = reinterpret_cast<const int4*>(et);

    for (int base = tid; base < E4; base += DEPTH * NT) {
        int4 S[DEPTH], D[DEPTH], T[DEPTH];
        // issue all loads back-to-back; clamp OOB to a valid address
#pragma unroll
        for (int k = 0; k < DEPTH; ++k) {
            int idx = base + k * NT;
            int cl = idx < E4 ? idx : (E4 - 1);
            S[k] = s4[cl];
            D[k] = d4[cl];
            T[k] = t4[cl];
        }
        // predicated accumulate: addend 0 for clamped (OOB) slots
#pragma unroll
        for (int k = 0; k < DEPTH; ++k) {
            const int add = (base + k * NT < E4) ? 1 : 0;
            atomicAdd(&bins[D[k].x * (RR * NN) + T[k].x * NN + S[k].x], add);
            atomicAdd(&bins[D[k].y * (RR * NN) + T[k].y * NN + S[k].y], add);
            atomicAdd(&bins[D[k].z * (RR * NN) + T[k].z * NN + S[k].z], add);
            atomicAdd(&bins[D[k].w * (RR * NN) + T[k].w * NN + S[k].w], add);
        }
    }
    // scalar tail (E not multiple of 4; never runs for E=8M)
    for (int e = (E4 << 2) + tid; e < E; e += NT) {
        atomicAdd(&bins[dst[e] * (RR * NN) + et[e] * NN + src[e]], 1);
    }

    __syncthreads();
    // plain coalesced store of the whole private histogram (incl. zeros)
    int* myslice = part + blockIdx.x * NBINS;
    for (int i2 = threadIdx.x; i2 < NBINS; i2 += HIST_BLOCK)
        myslice[i2] = bins[i2];
}

// ---------------------------------------------------------------------------
// Kernel 1b: reduce HIST_GRID partial histograms -> gbins. 49 blocks x 256
// threads; each block owns 64 bins; 4 chunks of HIST_GRID/4 partials per bin.
// Integer sums, fixed order -> deterministic & exact.
// ---------------------------------------------------------------------------
__global__ __launch_bounds__(256) void rgcn_reduce(
    const int* __restrict__ part, int* __restrict__ gbins) {
    __shared__ int acc[4][64];
    const int lane = threadIdx.x & 63;
    const int chunk = threadIdx.x >> 6;      // 0..3
    const int bin = blockIdx.x * 64 + lane;  // 49*64 = 3136 exactly

    int s = 0;
    const int p0 = chunk * (HIST_GRID / 4);
#pragma unroll 8
    for (int k = 0; k < HIST_GRID / 4; ++k)
        s += part[(p0 + k) * NBINS + bin];
    acc[chunk][lane] = s;
    __syncthreads();
    if (chunk == 0)
        gbins[bin] = acc[0][lane] + acc[1][lane] + acc[2][lane] + acc[3][lane];
}

// ---------------------------------------------------------------------------
// Kernel 2: everything else, single block of 512. W1/W2 staged into LDS.
// Long serial FMA chains split across threads with LDS partial reduces.
// ---------------------------------------------------------------------------
__global__ __launch_bounds__(512) void rgcn_finish(
    const int* __restrict__ gbins,
    const float* __restrict__ W1,    // [R][N][H]
    const float* __restrict__ root1, // [N][H]
    const float* __restrict__ b1,    // [H]
    const float* __restrict__ W2,    // [R][H][C]
    const float* __restrict__ root2, // [H][C]
    const float* __restrict__ b2,    // [C]
    float* __restrict__ out) {       // [N][C]
    __shared__ int   craw[NN][RR][NN];
    __shared__ float cntf[NN][RR][NN];
    __shared__ float w1s[RR * NN * HH]; // 7168 floats
    __shared__ float w2s[RR * HH * CC]; // 8192 floats
    __shared__ float p1[NN][HH][4];
    __shared__ float h[NN][HH];
    __shared__ float hr[NN][RR][CC];    // hr[src][r][c]
    __shared__ float p2[NN][CC][8];
    __shared__ float o[NN][CC];

    const int t = threadIdx.x;
    // stage everything (coalesced), single barrier
    for (int i = t; i < NBINS; i += blockDim.x)
        reinterpret_cast<int*>(craw)[i] = gbins[i];
    const float4* W1v = reinterpret_cast<const float4*>(W1);
    for (int i = t; i < RR * NN * HH / 4; i += blockDim.x)
        reinterpret_cast<float4*>(w1s)[i] = W1v[i];
    const float4* W2v = reinterpret_cast<const float4*>(W2);
    for (int i = t; i < RR * HH * CC / 4; i += blockDim.x)
        reinterpret_cast<float4*>(w2s)[i] = W2v[i];
    __syncthreads();

    // per-(dst, rel) totals -> normalized counts
    for (int i = t; i < NN * RR; i += blockDim.x) {
        int n = i / RR, r = i % RR;
        int tot = 0;
        for (int s = 0; s < NN; ++s) tot += craw[n][r][s];
        float inv = 1.0f / (float)(tot > 0 ? tot : 1);
        for (int s = 0; s < NN; ++s) cntf[n][r][s] = (float)craw[n][r][s] * inv;
    }
    __syncthreads();

    // layer 1 partials: (n,j,q), q sums r in [16q,16q+16)  — 448 threads
    for (int i = t; i < NN * HH * 4; i += blockDim.x) {
        int n = i >> 6;            // HH*4 = 64
        int j = (i >> 2) & (HH - 1);
        int q = i & 3;
        float acc = 0.0f;
        for (int r = q * 16; r < q * 16 + 16; ++r)
            for (int s = 0; s < NN; ++s)
                acc = fmaf(cntf[n][r][s], w1s[(r * NN + s) * HH + j], acc);
        p1[n][j][q] = acc;
    }
    __syncthreads();
    // layer 1 combine: h = relu(root1 + b1 + sum_q p1)
    for (int i = t; i < NN * HH; i += blockDim.x) {
        int n = i / HH, j = i % HH;
        float acc = root1[n * HH + j] + b1[j] +
                    p1[n][j][0] + p1[n][j][1] + p1[n][j][2] + p1[n][j][3];
        h[n][j] = fmaxf(acc, 0.0f);
    }
    __syncthreads();

    // hr[s][r][c] = sum_j h[s][j] * W2[r][j][c]   — 3584 outputs
    for (int i = t; i < NN * RR * CC; i += blockDim.x) {
        int s = i / (RR * CC);
        int rem = i % (RR * CC);
        int r = rem / CC, c = rem % CC;
        float acc = 0.0f;
        for (int j = 0; j < HH; ++j)
            acc = fmaf(h[s][j], w2s[(r * HH + j) * CC + c], acc);
        hr[s][r][c] = acc;
    }
    __syncthreads();

    // layer 2 partials: (n,c,q), q sums r in [8q,8q+8); q==0 adds root+bias
    for (int i = t; i < NN * CC * 8; i += blockDim.x) {
        int n = i >> 6;            // CC*8 = 64
        int c = (i >> 3) & (CC - 1);
        int q = i & 7;
        float acc = 0.0f;
        for (int r = q * 8; r < q * 8 + 8; ++r)
            for (int s = 0; s < NN; ++s)
                acc = fmaf(cntf[n][r][s], hr[s][r][c], acc);
        if (q == 0) {
            for (int j = 0; j < HH; ++j)
                acc = fmaf(h[n][j], root2[j * CC + c], acc);
            acc += b2[c];
        }
        p2[n][c][q] = acc;
    }
    __syncthreads();
    // layer 2 combine
    for (int i = t; i < NN * CC; i += blockDim.x) {
        int n = i / CC, c = i % CC;
        float acc = 0.0f;
        for (int q = 0; q < 8; ++q) acc += p2[n][c][q];
        o[n][c] = acc;
    }
    __syncthreads();

    // row-wise log_softmax, one thread per node
    if (t < NN) {
        float m = -1e30f;
        for (int c = 0; c < CC; ++c) m = fmaxf(m, o[t][c]);
        float sum = 0.0f;
        for (int c = 0; c < CC; ++c) sum += __expf(o[t][c] - m);
        float lse = m + __logf(sum);
        for (int c = 0; c < CC; ++c) out[t * CC + c] = o[t][c] - lse;
    }
}

extern "C" void kernel_launch(void* const* d_in, const int* in_sizes, int n_in,
                              void* d_out, int out_size, void* d_ws, size_t ws_size,
                              hipStream_t stream) {
    // input order: x, edge_index, edge_type, W1, root1, b1, W2, root2, b2
    const int* edge_index = (const int*)d_in[1];
    const int* edge_type  = (const int*)d_in[2];
    const float* W1    = (const float*)d_in[3];
    const float* root1 = (const float*)d_in[4];
    const float* b1    = (const float*)d_in[5];
    const float* W2    = (const float*)d_in[6];
    const float* root2 = (const float*)d_in[7];
    const float* b2    = (const float*)d_in[8];
    float* out = (float*)d_out;

    const int E = in_sizes[2];              // num edges
    const int* src = edge_index;            // edge_index[0]
    const int* dst = edge_index + E;        // edge_index[1]

    int* part  = (int*)d_ws;                       // 256 * 3136 ints = 3.2 MB
    int* gbins = part + HIST_GRID * NBINS;         // 3136 ints

    rgcn_hist<<<HIST_GRID, HIST_BLOCK, 0, stream>>>(src, dst, edge_type, E, part);
    rgcn_reduce<<<49, 256, 0, stream>>>(part, gbins);
    rgcn_finish<<<1, 512, 0, stream>>>(gbins, W1, root1, b1, W2, root2, b2, out);
}

// Round 7
// 41.571 us; speedup vs baseline: 1.0460x; 1.0460x over previous
//
#include <hip/hip_runtime.h>
#include <hip/hip_bf16.h>

#define NN 7
#define HH 16
#define RR 64
#define CC 8
#define NBINS (NN * RR * NN)   // 3136

#define HIST_BLOCK 512
#define HIST_GRID  256                       // 1 block/CU -> 8 waves/CU -> 256-VGPR budget
#define NTH (HIST_GRID * HIST_BLOCK)         // 131072 threads
#define DEPTH 16                             // ceil(E4/NTH) = 16 for E=8M -> single phase

// ---------------------------------------------------------------------------
// Kernel 1: histogram edges into (dst, rel, src) bins in LDS.
// Single-phase depth-16 barrage: 48 dwordx4 loads back-to-back per thread
// (slot 15 clamped), then 64 predicated LDS atomics. 2 waves/SIMD gives the
// 256-VGPR budget the barrage needs (R6 spilled at the 128-VGPR cap).
// ---------------------------------------------------------------------------
__global__ __launch_bounds__(HIST_BLOCK, 2) void rgcn_hist(
    const int* __restrict__ src, const int* __restrict__ dst,
    const int* __restrict__ et, int E, int* __restrict__ part) {
    __shared__ int bins[NBINS];
    for (int i = threadIdx.x; i < NBINS; i += HIST_BLOCK) bins[i] = 0;
    __syncthreads();

    const int tid = blockIdx.x * HIST_BLOCK + threadIdx.x;
    const int E4 = E >> 2;
    const int4* s4 = reinterpret_cast<const int4*>(src);
    const int4* d4 = reinterpret_cast<const int4*>(dst);
    const int4* t4 = reinterpret_cast<const int4*>(et);

    for (int base = tid; base < E4; base += DEPTH * NTH) {
        int4 S[DEPTH], D[DEPTH], T[DEPTH];
        // issue all loads back-to-back; clamp OOB to a valid address
#pragma unroll
        for (int k = 0; k < DEPTH; ++k) {
            int idx = base + k * NTH;
            int cl = idx < E4 ? idx : (E4 - 1);
            S[k] = s4[cl];
            D[k] = d4[cl];
            T[k] = t4[cl];
        }
        // predicated accumulate: addend 0 for clamped (OOB) slots
#pragma unroll
        for (int k = 0; k < DEPTH; ++k) {
            const int add = (base + k * NTH < E4) ? 1 : 0;
            atomicAdd(&bins[D[k].x * (RR * NN) + T[k].x * NN + S[k].x], add);
            atomicAdd(&bins[D[k].y * (RR * NN) + T[k].y * NN + S[k].y], add);
            atomicAdd(&bins[D[k].z * (RR * NN) + T[k].z * NN + S[k].z], add);
            atomicAdd(&bins[D[k].w * (RR * NN) + T[k].w * NN + S[k].w], add);
        }
    }
    // scalar tail (E not multiple of 4; never runs for E=8M)
    for (int e = (E4 << 2) + tid; e < E; e += NTH) {
        atomicAdd(&bins[dst[e] * (RR * NN) + et[e] * NN + src[e]], 1);
    }

    __syncthreads();
    // plain coalesced store of the whole private histogram (incl. zeros)
    int* myslice = part + blockIdx.x * NBINS;
    for (int i2 = threadIdx.x; i2 < NBINS; i2 += HIST_BLOCK)
        myslice[i2] = bins[i2];
}

// ---------------------------------------------------------------------------
// Kernel 1b: reduce HIST_GRID partial histograms -> gbins. 49 blocks x 256
// threads; each block owns 64 bins; 4 chunks of HIST_GRID/4 partials per bin.
// Integer sums, fixed order -> deterministic & exact.
// ---------------------------------------------------------------------------
__global__ __launch_bounds__(256) void rgcn_reduce(
    const int* __restrict__ part, int* __restrict__ gbins) {
    __shared__ int acc[4][64];
    const int lane = threadIdx.x & 63;
    const int chunk = threadIdx.x >> 6;      // 0..3
    const int bin = blockIdx.x * 64 + lane;  // 49*64 = 3136 exactly

    int s = 0;
    const int p0 = chunk * (HIST_GRID / 4);
#pragma unroll 8
    for (int k = 0; k < HIST_GRID / 4; ++k)
        s += part[(p0 + k) * NBINS + bin];
    acc[chunk][lane] = s;
    __syncthreads();
    if (chunk == 0)
        gbins[bin] = acc[0][lane] + acc[1][lane] + acc[2][lane] + acc[3][lane];
}

// ---------------------------------------------------------------------------
// Kernel 2: everything else, single block of 512. W1/W2 staged into LDS.
// Long serial FMA chains split across threads with LDS partial reduces.
// ---------------------------------------------------------------------------
__global__ __launch_bounds__(512) void rgcn_finish(
    const int* __restrict__ gbins,
    const float* __restrict__ W1,    // [R][N][H]
    const float* __restrict__ root1, // [N][H]
    const float* __restrict__ b1,    // [H]
    const float* __restrict__ W2,    // [R][H][C]
    const float* __restrict__ root2, // [H][C]
    const float* __restrict__ b2,    // [C]
    float* __restrict__ out) {       // [N][C]
    __shared__ int   craw[NN][RR][NN];
    __shared__ float cntf[NN][RR][NN];
    __shared__ float w1s[RR * NN * HH]; // 7168 floats
    __shared__ float w2s[RR * HH * CC]; // 8192 floats
    __shared__ float p1[NN][HH][4];
    __shared__ float h[NN][HH];
    __shared__ float hr[NN][RR][CC];    // hr[src][r][c]
    __shared__ float p2[NN][CC][8];
    __shared__ float o[NN][CC];

    const int t = threadIdx.x;
    // stage everything (coalesced), single barrier
    for (int i = t; i < NBINS; i += blockDim.x)
        reinterpret_cast<int*>(craw)[i] = gbins[i];
    const float4* W1v = reinterpret_cast<const float4*>(W1);
    for (int i = t; i < RR * NN * HH / 4; i += blockDim.x)
        reinterpret_cast<float4*>(w1s)[i] = W1v[i];
    const float4* W2v = reinterpret_cast<const float4*>(W2);
    for (int i = t; i < RR * HH * CC / 4; i += blockDim.x)
        reinterpret_cast<float4*>(w2s)[i] = W2v[i];
    __syncthreads();

    // per-(dst, rel) totals -> normalized counts
    for (int i = t; i < NN * RR; i += blockDim.x) {
        int n = i / RR, r = i % RR;
        int tot = 0;
        for (int s = 0; s < NN; ++s) tot += craw[n][r][s];
        float inv = 1.0f / (float)(tot > 0 ? tot : 1);
        for (int s = 0; s < NN; ++s) cntf[n][r][s] = (float)craw[n][r][s] * inv;
    }
    __syncthreads();

    // layer 1 partials: (n,j,q), q sums r in [16q,16q+16)  — 448 threads
    for (int i = t; i < NN * HH * 4; i += blockDim.x) {
        int n = i >> 6;            // HH*4 = 64
        int j = (i >> 2) & (HH - 1);
        int q = i & 3;
        float acc = 0.0f;
        for (int r = q * 16; r < q * 16 + 16; ++r)
            for (int s = 0; s < NN; ++s)
                acc = fmaf(cntf[n][r][s], w1s[(r * NN + s) * HH + j], acc);
        p1[n][j][q] = acc;
    }
    __syncthreads();
    // layer 1 combine: h = relu(root1 + b1 + sum_q p1)
    for (int i = t; i < NN * HH; i += blockDim.x) {
        int n = i / HH, j = i % HH;
        float acc = root1[n * HH + j] + b1[j] +
                    p1[n][j][0] + p1[n][j][1] + p1[n][j][2] + p1[n][j][3];
        h[n][j] = fmaxf(acc, 0.0f);
    }
    __syncthreads();

    // hr[s][r][c] = sum_j h[s][j] * W2[r][j][c]   — 3584 outputs
    for (int i = t; i < NN * RR * CC; i += blockDim.x) {
        int s = i / (RR * CC);
        int rem = i % (RR * CC);
        int r = rem / CC, c = rem % CC;
        float acc = 0.0f;
        for (int j = 0; j < HH; ++j)
            acc = fmaf(h[s][j], w2s[(r * HH + j) * CC + c], acc);
        hr[s][r][c] = acc;
    }
    __syncthreads();

    // layer 2 partials: (n,c,q), q sums r in [8q,8q+8); q==0 adds root+bias
    for (int i = t; i < NN * CC * 8; i += blockDim.x) {
        int n = i >> 6;            // CC*8 = 64
        int c = (i >> 3) & (CC - 1);
        int q = i & 7;
        float acc = 0.0f;
        for (int r = q * 8; r < q * 8 + 8; ++r)
            for (int s = 0; s < NN; ++s)
                acc = fmaf(cntf[n][r][s], hr[s][r][c], acc);
        if (q == 0) {
            for (int j = 0; j < HH; ++j)
                acc = fmaf(h[n][j], root2[j * CC + c], acc);
            acc += b2[c];
        }
        p2[n][c][q] = acc;
    }
    __syncthreads();
    // layer 2 combine
    for (int i = t; i < NN * CC; i += blockDim.x) {
        int n = i / CC, c = i % CC;
        float acc = 0.0f;
        for (int q = 0; q < 8; ++q) acc += p2[n][c][q];
        o[n][c] = acc;
    }
    __syncthreads();

    // row-wise log_softmax, one thread per node
    if (t < NN) {
        float m = -1e30f;
        for (int c = 0; c < CC; ++c) m = fmaxf(m, o[t][c]);
        float sum = 0.0f;
        for (int c = 0; c < CC; ++c) sum += __expf(o[t][c] - m);
        float lse = m + __logf(sum);
        for (int c = 0; c < CC; ++c) out[t * CC + c] = o[t][c] - lse;
    }
}

extern "C" void kernel_launch(void* const* d_in, const int* in_sizes, int n_in,
                              void* d_out, int out_size, void* d_ws, size_t ws_size,
                              hipStream_t stream) {
    // input order: x, edge_index, edge_type, W1, root1, b1, W2, root2, b2
    const int* edge_index = (const int*)d_in[1];
    const int* edge_type  = (const int*)d_in[2];
    const float* W1    = (const float*)d_in[3];
    const float* root1 = (const float*)d_in[4];
    const float* b1    = (const float*)d_in[5];
    const float* W2    = (const float*)d_in[6];
    const float* root2 = (const float*)d_in[7];
    const float* b2    = (const float*)d_in[8];
    float* out = (float*)d_out;

    const int E = in_sizes[2];              // num edges
    const int* src = edge_index;            // edge_index[0]
    const int* dst = edge_index + E;        // edge_index[1]

    int* part  = (int*)d_ws;                       // 256 * 3136 ints = 3.2 MB
    int* gbins = part + HIST_GRID * NBINS;         // 3136 ints

    rgcn_hist<<<HIST_GRID, HIST_BLOCK, 0, stream>>>(src, dst, edge_type, E, part);
    rgcn_reduce<<<49, 256, 0, stream>>>(part, gbins);
    rgcn_finish<<<1, 512, 0, stream>>>(gbins, W1, root1, b1, W2, root2, b2, out);
}

// Round 8
// 37.796 us; speedup vs baseline: 1.1505x; 1.0999x over previous
//
#include <hip/hip_runtime.h>
#include <hip/hip_bf16.h>

#define NN 7
#define HH 16
#define RR 64
#define CC 8
#define NBINS (NN * RR * NN)   // 3136

#define HIST_BLOCK 1024
#define HIST_GRID  256                      // 1 block/CU, 16 waves/CU, 128-VGPR budget
#define NT (HIST_GRID * HIST_BLOCK)         // 262144 threads

// ---------------------------------------------------------------------------
// Kernel 1: histogram edges into (dst, rel, src) bins in LDS.
// Full-coverage depth-4 pipeline (R5's proven VGPR sweet spot, R6/R7 showed
// deeper spills): every phase issues 12 dwordx4 loads back-to-back; the
// final phase clamps OOB indices and predicates the atomic addend to 0 —
// NO serial depth-1 remainder loop (R5's defect: 63% of threads did their
// last 3-4 triples with exposed latency).
// ---------------------------------------------------------------------------
__global__ __launch_bounds__(HIST_BLOCK) void rgcn_hist(
    const int* __restrict__ src, const int* __restrict__ dst,
    const int* __restrict__ et, int E, int* __restrict__ part) {
    __shared__ int bins[NBINS];
    for (int i = threadIdx.x; i < NBINS; i += HIST_BLOCK) bins[i] = 0;
    __syncthreads();

    const int tid = blockIdx.x * HIST_BLOCK + threadIdx.x;
    const int E4 = E >> 2;
    const int4* s4 = reinterpret_cast<const int4*>(src);
    const int4* d4 = reinterpret_cast<const int4*>(dst);
    const int4* t4 = reinterpret_cast<const int4*>(et);

    for (int base = tid; base < E4; base += 4 * NT) {
        int4 S[4], D[4], T[4];
#pragma unroll
        for (int k = 0; k < 4; ++k) {
            int idx = base + k * NT;
            int cl = idx < E4 ? idx : (E4 - 1);   // clamp OOB to valid addr
            S[k] = s4[cl];
            D[k] = d4[cl];
            T[k] = t4[cl];
        }
#pragma unroll
        for (int k = 0; k < 4; ++k) {
            const int add = (base + k * NT < E4) ? 1 : 0;  // predicate OOB
            atomicAdd(&bins[D[k].x * (RR * NN) + T[k].x * NN + S[k].x], add);
            atomicAdd(&bins[D[k].y * (RR * NN) + T[k].y * NN + S[k].y], add);
            atomicAdd(&bins[D[k].z * (RR * NN) + T[k].z * NN + S[k].z], add);
            atomicAdd(&bins[D[k].w * (RR * NN) + T[k].w * NN + S[k].w], add);
        }
    }
    // scalar tail (E not multiple of 4; never runs for E=8M)
    for (int e = (E4 << 2) + tid; e < E; e += NT) {
        atomicAdd(&bins[dst[e] * (RR * NN) + et[e] * NN + src[e]], 1);
    }

    __syncthreads();
    // plain coalesced store of the whole private histogram (incl. zeros)
    int* myslice = part + blockIdx.x * NBINS;
    for (int i2 = threadIdx.x; i2 < NBINS; i2 += HIST_BLOCK)
        myslice[i2] = bins[i2];
}

// ---------------------------------------------------------------------------
// Kernel 1b: reduce HIST_GRID partial histograms -> gbins. 49 blocks x 256
// threads; each block owns 64 bins; 4 chunks of HIST_GRID/4 partials per bin.
// Integer sums, fixed order -> deterministic & exact.
// ---------------------------------------------------------------------------
__global__ __launch_bounds__(256) void rgcn_reduce(
    const int* __restrict__ part, int* __restrict__ gbins) {
    __shared__ int acc[4][64];
    const int lane = threadIdx.x & 63;
    const int chunk = threadIdx.x >> 6;      // 0..3
    const int bin = blockIdx.x * 64 + lane;  // 49*64 = 3136 exactly

    int s = 0;
    const int p0 = chunk * (HIST_GRID / 4);
#pragma unroll 8
    for (int k = 0; k < HIST_GRID / 4; ++k)
        s += part[(p0 + k) * NBINS + bin];
    acc[chunk][lane] = s;
    __syncthreads();
    if (chunk == 0)
        gbins[bin] = acc[0][lane] + acc[1][lane] + acc[2][lane] + acc[3][lane];
}

// ---------------------------------------------------------------------------
// Kernel 2: everything else, single block of 1024. W1/W2 staged into LDS;
// cntf computed directly from gbins (no craw stage, one less barrier).
// Long serial FMA chains split across threads with LDS partial reduces.
// ---------------------------------------------------------------------------
__global__ __launch_bounds__(1024) void rgcn_finish(
    const int* __restrict__ gbins,
    const float* __restrict__ W1,    // [R][N][H]
    const float* __restrict__ root1, // [N][H]
    const float* __restrict__ b1,    // [H]
    const float* __restrict__ W2,    // [R][H][C]
    const float* __restrict__ root2, // [H][C]
    const float* __restrict__ b2,    // [C]
    float* __restrict__ out) {       // [N][C]
    __shared__ float cntf[NN][RR][NN];
    __shared__ float w1s[RR * NN * HH]; // 7168 floats
    __shared__ float w2s[RR * HH * CC]; // 8192 floats
    __shared__ float p1[NN][HH][4];
    __shared__ float h[NN][HH];
    __shared__ float hr[NN][RR][CC];    // hr[src][r][c]
    __shared__ float p2[NN][CC][8];
    __shared__ float o[NN][CC];

    const int t = threadIdx.x;
    const int BD = 1024;
    // stage weights (coalesced float4) + normalized counts, single barrier
    const float4* W1v = reinterpret_cast<const float4*>(W1);
    for (int i = t; i < RR * NN * HH / 4; i += BD)
        reinterpret_cast<float4*>(w1s)[i] = W1v[i];
    const float4* W2v = reinterpret_cast<const float4*>(W2);
    for (int i = t; i < RR * HH * CC / 4; i += BD)
        reinterpret_cast<float4*>(w2s)[i] = W2v[i];
    for (int i = t; i < NN * RR; i += BD) {
        int n = i / RR, r = i % RR;
        const int* gb = gbins + n * (RR * NN) + r * NN;
        int c[NN];
        int tot = 0;
#pragma unroll
        for (int s = 0; s < NN; ++s) { c[s] = gb[s]; tot += c[s]; }
        float inv = 1.0f / (float)(tot > 0 ? tot : 1);
#pragma unroll
        for (int s = 0; s < NN; ++s) cntf[n][r][s] = (float)c[s] * inv;
    }
    __syncthreads();

    // layer 1 partials: (n,j,q), q sums r in [16q,16q+16)  — 448 threads
    for (int i = t; i < NN * HH * 4; i += BD) {
        int n = i >> 6;            // HH*4 = 64
        int j = (i >> 2) & (HH - 1);
        int q = i & 3;
        float acc = 0.0f;
        for (int r = q * 16; r < q * 16 + 16; ++r)
            for (int s = 0; s < NN; ++s)
                acc = fmaf(cntf[n][r][s], w1s[(r * NN + s) * HH + j], acc);
        p1[n][j][q] = acc;
    }
    __syncthreads();
    // layer 1 combine: h = relu(root1 + b1 + sum_q p1)
    for (int i = t; i < NN * HH; i += BD) {
        int n = i / HH, j = i % HH;
        float acc = root1[n * HH + j] + b1[j] +
                    p1[n][j][0] + p1[n][j][1] + p1[n][j][2] + p1[n][j][3];
        h[n][j] = fmaxf(acc, 0.0f);
    }
    __syncthreads();

    // hr[s][r][c] = sum_j h[s][j] * W2[r][j][c]   — 3584 outputs
    for (int i = t; i < NN * RR * CC; i += BD) {
        int s = i / (RR * CC);
        int rem = i % (RR * CC);
        int r = rem / CC, c = rem % CC;
        float acc = 0.0f;
        for (int j = 0; j < HH; ++j)
            acc = fmaf(h[s][j], w2s[(r * HH + j) * CC + c], acc);
        hr[s][r][c] = acc;
    }
    __syncthreads();

    // layer 2 partials: (n,c,q), q sums r in [8q,8q+8); q==0 adds root+bias
    for (int i = t; i < NN * CC * 8; i += BD) {
        int n = i >> 6;            // CC*8 = 64
        int c = (i >> 3) & (CC - 1);
        int q = i & 7;
        float acc = 0.0f;
        for (int r = q * 8; r < q * 8 + 8; ++r)
            for (int s = 0; s < NN; ++s)
                acc = fmaf(cntf[n][r][s], hr[s][r][c], acc);
        if (q == 0) {
            for (int j = 0; j < HH; ++j)
                acc = fmaf(h[n][j], root2[j * CC + c], acc);
            acc += b2[c];
        }
        p2[n][c][q] = acc;
    }
    __syncthreads();
    // layer 2 combine
    for (int i = t; i < NN * CC; i += BD) {
        int n = i / CC, c = i % CC;
        float acc = 0.0f;
        for (int q = 0; q < 8; ++q) acc += p2[n][c][q];
        o[n][c] = acc;
    }
    __syncthreads();

    // row-wise log_softmax, one thread per node
    if (t < NN) {
        float m = -1e30f;
        for (int c = 0; c < CC; ++c) m = fmaxf(m, o[t][c]);
        float sum = 0.0f;
        for (int c = 0; c < CC; ++c) sum += __expf(o[t][c] - m);
        float lse = m + __logf(sum);
        for (int c = 0; c < CC; ++c) out[t * CC + c] = o[t][c] - lse;
    }
}

extern "C" void kernel_launch(void* const* d_in, const int* in_sizes, int n_in,
                              void* d_out, int out_size, void* d_ws, size_t ws_size,
                              hipStream_t stream) {
    // input order: x, edge_index, edge_type, W1, root1, b1, W2, root2, b2
    const int* edge_index = (const int*)d_in[1];
    const int* edge_type  = (const int*)d_in[2];
    const float* W1    = (const float*)d_in[3];
    const float* root1 = (const float*)d_in[4];
    const float* b1    = (const float*)d_in[5];
    const float* W2    = (const float*)d_in[6];
    const float* root2 = (const float*)d_in[7];
    const float* b2    = (const float*)d_in[8];
    float* out = (float*)d_out;

    const int E = in_sizes[2];              // num edges
    const int* src = edge_index;            // edge_index[0]
    const int* dst = edge_index + E;        // edge_index[1]

    int* part  = (int*)d_ws;                       // 256 * 3136 ints = 3.2 MB
    int* gbins = part + HIST_GRID * NBINS;         // 3136 ints

    rgcn_hist<<<HIST_GRID, HIST_BLOCK, 0, stream>>>(src, dst, edge_type, E, part);
    rgcn_reduce<<<49, 256, 0, stream>>>(part, gbins);
    rgcn_finish<<<1, 1024, 0, stream>>>(gbins, W1, root1, b1, W2, root2, b2, out);
}